// Round 15
// baseline (316.824 us; speedup 1.0000x reference)
//
#include <hip/hip_runtime.h>

// Problem constants (fixed by the reference)
#define BB 16
#define HIS 13
#define NN 400
#define DIN 16
#define HID 256
#define PRED 12
#define NE 9600
#define EPSF 1e-5f
#define HSZ ((size_t)25600*256)            // full h element count (LN stats denom)
#define BAND ((size_t)NN*BB*HID)           // 1,638,400 elems (one t-band)
#define ROWS_BAND (NN*BB)                  // 6400 rows per band
#define CSR_CAP 6144

typedef __attribute__((ext_vector_type(8))) short short8v;
typedef __attribute__((ext_vector_type(4))) float f32x4;

__device__ __forceinline__ short f2bf(float x) {
    unsigned u = __float_as_uint(x);
    return (short)((u + 0x7FFF + ((u >> 16) & 1)) >> 16);
}
__device__ __forceinline__ float bf2f(short x) {
    return __uint_as_float(((unsigned)(unsigned short)x) << 16);
}

// ------------------------------------------------------------ fused prep
// (verbatim round 14 — proven best)
__global__ __launch_bounds__(256) void k_prep(
    const int* __restrict__ src, const int* __restrict__ dst,
    const float* __restrict__ ew, const float* __restrict__ gcn_W,
    const float* __restrict__ inp, const float* __restrict__ W_in,
    const float* __restrict__ b_in, const float* __restrict__ gb2,
    float* __restrict__ inv_in, float* __restrict__ csum,
    int* __restrict__ csr_off, int* __restrict__ csr_src,
    float* __restrict__ cf1, float* __restrict__ cf2,
    short* __restrict__ Wt, short* __restrict__ xproj,
    float* __restrict__ stats)
{
    __shared__ __align__(16) char SM[17408];
    int t = threadIdx.x, bi = blockIdx.x;
    if (bi == 0) {
        int* ideg  = (int*)SM;             // 400
        int* cnt   = ideg + 400;           // 400
        int* offl  = cnt + 400;            // 401
        int* scan_t = offl + 401;          // 256
        float* csuml = (float*)(scan_t + 256); // 400
        for (int g = t; g < 400; g += 256) { ideg[g] = 0; cnt[g] = 0; csuml[g] = 0.f; }
        if (t == 9) stats[9] = (1.0f - EPSF) * (float)HSZ;   // identity affine slot
        __syncthreads();
        for (int e = t; e < 3200; e += 256) atomicAdd(&ideg[dst[e]], 1);
        __syncthreads();
        int s = 0, p0 = 0, p1 = 0;
        if (t < 200) {
            p0 = (ideg[2 * t] + 7) & ~7;
            p1 = (ideg[2 * t + 1] + 7) & ~7;
            s = p0 + p1;
        }
        scan_t[t] = s;
        __syncthreads();
        for (int o = 1; o < 256; o <<= 1) {
            int v = (t >= o) ? scan_t[t - o] : 0;
            __syncthreads();
            scan_t[t] += v;
            __syncthreads();
        }
        if (t < 200) { int base = scan_t[t] - s; offl[2 * t] = base; offl[2 * t + 1] = base + p0; }
        if (t == 255) offl[400] = scan_t[255];
        __syncthreads();
        int cap = offl[400];
        for (int g = t; g < 401; g += 256) csr_off[g] = offl[g];
        for (int g = t; g < 400; g += 256) inv_in[g] = rsqrtf(fmaxf((float)ideg[g], 1.f));
        for (int i = t; i < cap; i += 256) { csr_src[i] = 0; cf1[i] = 0.f; cf2[i] = 0.f; }
        __syncthreads();
        float rs16 = rsqrtf(16.0f), rs8 = rsqrtf(8.0f);
        for (int e = t; e < 3200; e += 256) {
            int d = dst[e];
            int r = e >> 3;                 // src structure: repeat(arange(400), 8)
            int p = offl[d] + atomicAdd(&cnt[d], 1);
            float w = ew[e];
            float c1 = w * rs16;
            csr_src[p] = r;
            cf1[p] = c1;
            cf2[p] = w * rs8;
            atomicAdd(&csuml[d], c1);
        }
        __syncthreads();
        for (int g = t; g < 400; g += 256) csum[g] = csuml[g];
    } else if (bi <= 48) {
        float (*S)[65] = (float(*)[65])SM;
        int tile = bi - 1;
        int l = tile / 16, sub = tile % 16;
        int k0 = (sub >> 2) * 64, n0 = (sub & 3) * 64;
        int tr = t >> 6, tc = t & 63;
#pragma unroll
        for (int i = 0; i < 16; ++i) {
            int r = i * 4 + tr;
            S[r][tc] = gcn_W[(size_t)l * 65536 + (size_t)(k0 + r) * 256 + n0 + tc];
        }
        __syncthreads();
#pragma unroll
        for (int i = 0; i < 16; ++i) {
            int n = i * 4 + tr;
            Wt[(size_t)l * 65536 + (size_t)(n0 + n) * 256 + k0 + tc] = f2bf(S[tc][n]);
        }
    } else {
        float* rbuf = (float*)SM;
        float wr[16];
#pragma unroll
        for (int d = 0; d < 16; ++d) wr[d] = W_in[d * 256 + t];
        float bvv = b_in[t];
        int job0 = (bi - 49) * 4;
        int time = job0 / 400;
        int n0 = job0 % 400;
        bool isStat = (time == 2 || time == 5 || time == 8 || time == 11);
        float gb = isStat ? gb2[t] : 0.f;
        float s1 = 0.f, s2 = 0.f;
        for (int j = 0; j < 4; ++j) {
            int n = n0 + j;
            float acc[16];
#pragma unroll
            for (int b = 0; b < 16; ++b) acc[b] = bvv;
#pragma unroll
            for (int b = 0; b < 16; ++b) {
                const float* xr = inp + (((size_t)b * HIS + time) * NN + n) * DIN;
#pragma unroll
                for (int d = 0; d < 16; ++d) acc[b] = fmaf(xr[d], wr[d], acc[b]);
            }
            if (isStat) {
#pragma unroll
                for (int b = 0; b < 16; ++b) {
                    float v = acc[b] + gb;
                    s1 += v; s2 += v * v;
                }
            } else {
                size_t gbase = (size_t)time * BAND + ((size_t)n * 16) * 256 + t;
#pragma unroll
                for (int b = 0; b < 16; ++b) xproj[gbase + (size_t)b * 256] = f2bf(acc[b]);
            }
        }
        if (isStat) {
#pragma unroll
            for (int o = 32; o > 0; o >>= 1) {
                s1 += __shfl_down(s1, o, 64);
                s2 += __shfl_down(s2, o, 64);
            }
            int wid = t >> 6, lane = t & 63;
            if (lane == 0) { rbuf[wid] = s1; rbuf[4 + wid] = s2; }
            __syncthreads();
            if (t == 0) {
                int it = (time - 2) / 3;
                atomicAdd(&stats[it * 2],     rbuf[0] + rbuf[1] + rbuf[2] + rbuf[3]);
                atomicAdd(&stats[it * 2 + 1], rbuf[4] + rbuf[5] + rbuf[6] + rbuf[7]);
            }
        }
    }
}

// ------------------------------------------------------------ fused agg + MFMA GEMM
// Round-7 schedule (400 blocks, 2 g's each). B slab held in REGISTERS
// (128 VGPR/lane, loaded once from L2) instead of double-buffered LDS:
// MFMA loop has no barriers and no staging. 2 barriers total.
template <int MODE>
__global__ __launch_bounds__(256) void k_layer(
    const short* __restrict__ hX, const short* __restrict__ hY,
    const float* __restrict__ stA, const float* __restrict__ csum,
    const float* __restrict__ inv_in, const int* __restrict__ csr_off,
    const int* __restrict__ csr_src, const float* __restrict__ cf1,
    const float* __restrict__ cf2,
    const short* __restrict__ Bt, const float* __restrict__ bias,
    const short* __restrict__ resX0, const float* __restrict__ stR,
    const short* __restrict__ resX1, const short* __restrict__ resY,
    short* __restrict__ C, float* __restrict__ stats)
{
    __shared__ short As[32][264];
    __shared__ float red[512];
    int tid = threadIdx.x;
    int wid = tid >> 6, l = tid & 63;
    int l15 = l & 15, l4 = l >> 4;
    int blk = blockIdx.x;
    int isY = blk >= 200;
    int gl = (isY ? blk - 200 : blk) * 2;
    int rowL0 = gl * 16;
    int wn = wid * 64;
    const short* hsrc = isY ? hY : hX;
    const float* cf = isY ? cf2 : cf1;

    float am = 1.f, moff = 0.f;
    if (MODE == 0 && !isY) {
        float mean = stA[0] * (1.f / (float)HSZ);
        float var  = stA[1] * (1.f / (float)HSZ) - mean * mean;
        float istd = rsqrtf(var + EPSF);
        am = istd; moff = mean * istd;
    }

    // ---- gather: 2 g's, padded 8-edge chunks (verbatim round 7)
    {
        int b = tid >> 4, hsc = (tid & 15) * 16;
        const size_t lane_off = (size_t)b * HID + hsc;
        for (int gi = 0; gi < 2; ++gi) {
            int g = gl + gi;
            int beg = csr_off[g], end = csr_off[g + 1];
            float acc[16];
#pragma unroll
            for (int i = 0; i < 16; ++i) acc[i] = 0.f;
            for (int j = beg; j < end; j += 8) {
                int ss[8]; float cc[8];
#pragma unroll
                for (int u = 0; u < 8; ++u) { ss[u] = csr_src[j + u]; cc[u] = cf[j + u]; }
                short8v va[8], vb[8];
#pragma unroll
                for (int u = 0; u < 8; ++u) {
                    const short8v* q = (const short8v*)&hsrc[(size_t)ss[u] * 4096 + lane_off];
                    va[u] = q[0]; vb[u] = q[1];
                }
#pragma unroll
                for (int u = 0; u < 8; ++u) {
#pragma unroll
                    for (int i = 0; i < 8; ++i) {
                        acc[i]     = fmaf(cc[u], bf2f(va[u][i]), acc[i]);
                        acc[8 + i] = fmaf(cc[u], bf2f(vb[u][i]), acc[8 + i]);
                    }
                }
            }
            float s = inv_in[g];
            float addv = (MODE == 0 && !isY) ? (-moff * csum[g]) : 0.f;
            short8v o0, o1;
#pragma unroll
            for (int i = 0; i < 8; ++i) o0[i] = f2bf(s * fmaf(am, acc[i], addv));
#pragma unroll
            for (int i = 0; i < 8; ++i) o1[i] = f2bf(s * fmaf(am, acc[8 + i], addv));
            int row = gi * 16 + b;
            *(short8v*)&As[row][hsc]     = o0;
            *(short8v*)&As[row][hsc + 8] = o1;
        }
    }

    // ---- load the wave's B slab into registers (issued before the barrier
    //      so the loads drain while waiting on gather stragglers)
    short8v breg[4][8];
#pragma unroll
    for (int ni = 0; ni < 4; ++ni)
#pragma unroll
        for (int kc = 0; kc < 8; ++kc)
            breg[ni][kc] = *(const short8v*)
                &Bt[(size_t)(wn + ni * 16 + l15) * 256 + kc * 32 + l4 * 8];

    __syncthreads();

    // ---- MFMA loop: no barriers, no staging
    f32x4 cacc[2][4] = {};
#pragma unroll
    for (int kc = 0; kc < 8; ++kc) {
        int k0 = kc * 32;
        short8v av[2];
        av[0] = *(const short8v*)&As[l15][k0 + l4 * 8];
        av[1] = *(const short8v*)&As[16 + l15][k0 + l4 * 8];
#pragma unroll
        for (int mi = 0; mi < 2; ++mi)
#pragma unroll
            for (int ni = 0; ni < 4; ++ni)
                cacc[mi][ni] = __builtin_amdgcn_mfma_f32_16x16x32_bf16(
                    av[mi], breg[ni][kc], cacc[mi][ni], 0, 0, 0);
    }
    __syncthreads();   // all waves done reading As before epilogue reuses it

    if (MODE <= 1) {
#pragma unroll
        for (int ni = 0; ni < 4; ++ni) {
            int col = wn + ni * 16 + l15;
            float bvv = bias[col];
#pragma unroll
            for (int mi = 0; mi < 2; ++mi) {
#pragma unroll
                for (int r = 0; r < 4; ++r) {
                    float v = fmaxf(cacc[mi][ni][r] + bvv, 0.f);
                    As[mi * 16 + l4 * 4 + r][col] = f2bf(v);
                }
            }
        }
        __syncthreads();
        int row = tid >> 3, cs = (tid & 7) * 32;
        size_t gb = ((size_t)(isY ? ROWS_BAND : 0) + rowL0 + row) * HID + cs;
#pragma unroll
        for (int i = 0; i < 4; ++i)
            *(short8v*)&C[gb + i * 8] = *(const short8v*)&As[row][cs + i * 8];
    } else {
        float s1 = 0.f, s2 = 0.f;
        if (!isY) {
            float meanR = stR[0] * (1.f / (float)HSZ);
            float varR  = stR[1] * (1.f / (float)HSZ) - meanR * meanR;
            float istdR = rsqrtf(varR + EPSF);
#pragma unroll
            for (int ni = 0; ni < 4; ++ni) {
                int col = wn + ni * 16 + l15;
                float bvv = bias[col];
#pragma unroll
                for (int mi = 0; mi < 2; ++mi) {
#pragma unroll
                    for (int r = 0; r < 4; ++r) {
                        int rowg = rowL0 + mi * 16 + l4 * 4 + r;
                        size_t ix = (size_t)rowg * HID + col;
                        float base = cacc[mi][ni][r] + bvv;
                        float v1 = base + (bf2f(resX0[ix]) - meanR) * istdR;
                        float v2 = base + bf2f(resX1[ix]);
                        s1 += v1 + v2;
                        s2 += v1 * v1 + v2 * v2;
                    }
                }
            }
        } else {
#pragma unroll
            for (int ni = 0; ni < 4; ++ni) {
                int col = wn + ni * 16 + l15;
                float bvv = bias[col];
#pragma unroll
                for (int mi = 0; mi < 2; ++mi) {
#pragma unroll
                    for (int r = 0; r < 4; ++r) {
                        int rowl = mi * 16 + l4 * 4 + r;
                        size_t ix = (size_t)(rowL0 + rowl) * HID + col;
                        float v = cacc[mi][ni][r] + bvv + bf2f(resY[ix]);
                        s1 += v; s2 += v * v;
                        As[rowl][col] = f2bf(v);
                    }
                }
            }
            __syncthreads();
            int row = tid >> 3, cs = (tid & 7) * 32;
            size_t gb = (size_t)(rowL0 + row) * HID + cs;
#pragma unroll
            for (int i = 0; i < 4; ++i)
                *(short8v*)&C[gb + i * 8] = *(const short8v*)&As[row][cs + i * 8];
        }
        red[tid] = s1; red[256 + tid] = s2;
        __syncthreads();
        for (int o = 128; o > 0; o >>= 1) {
            if (tid < o) { red[tid] += red[tid + o]; red[256 + tid] += red[256 + tid + o]; }
            __syncthreads();
        }
        if (tid == 0) { atomicAdd(&stats[0], red[0]); atomicAdd(&stats[1], red[256]); }
    }
}

// ---------------------------------------------------------------- head
__global__ void k_head(const short* __restrict__ hlast, const float* __restrict__ st,
                       const float* __restrict__ W1, const float* __restrict__ b1,
                       const float* __restrict__ W2, const float* __restrict__ b2,
                       float* __restrict__ out) {
    float mean = st[0] * (1.0f / (float)HSZ);
    float var  = st[1] * (1.0f / (float)HSZ) - mean * mean;
    float istd = rsqrtf(var + EPSF);
    int n = blockIdx.x, b = blockIdx.y, tid = threadIdx.x;
    float v  = (bf2f(hlast[((size_t)n * BB + b) * HID + tid]) - mean) * istd;
    float w2 = W2[tid];
    float b2v = b2[0];
    __shared__ float ps[4];
    for (int p = 0; p < PRED; ++p) {
        float t = fmaxf(fmaf(v, W1[p], b1[p]), 0.f) * w2;
#pragma unroll
        for (int o = 32; o > 0; o >>= 1) t += __shfl_down(t, o, 64);
        int wid = tid >> 6, lane = tid & 63;
        if (lane == 0) ps[wid] = t;
        __syncthreads();
        if (tid == 0) out[(size_t)(b * PRED + p) * NN + n] = ps[0] + ps[1] + ps[2] + ps[3] + b2v;
        __syncthreads();
    }
}

// ---------------------------------------------------------------- launch
extern "C" void kernel_launch(void* const* d_in, const int* in_sizes, int n_in,
                              void* d_out, int out_size, void* d_ws, size_t ws_size,
                              hipStream_t stream) {
    const float* inp   = (const float*)d_in[0];
    const float* W_in  = (const float*)d_in[1];
    const float* b_in  = (const float*)d_in[2];
    const float* gcn_W = (const float*)d_in[3];
    const float* gcn_b = (const float*)d_in[4];
    const float* W1    = (const float*)d_in[5];
    const float* b1    = (const float*)d_in[6];
    const float* W2    = (const float*)d_in[7];
    const float* b2    = (const float*)d_in[8];
    const float* ew    = (const float*)d_in[9];
    const int*   src   = (const int*)d_in[10];
    const int*   dst   = (const int*)d_in[11];
    float* out = (float*)d_out;

    char* w = (char*)d_ws;
    auto alloc = [&](size_t bytes) {
        char* p = w;
        w += (bytes + 255) & ~(size_t)255;
        return p;
    };
    short* hA    = (short*)alloc((size_t)2 * ROWS_BAND * HID * 2);  // compact [X|Y]
    short* hB    = (short*)alloc((size_t)2 * ROWS_BAND * HID * 2);
    short* hl0   = (short*)alloc(BAND * 2);
    short* hl1   = (short*)alloc(BAND * 2);
    short* xproj = (short*)alloc((size_t)13 * BAND * 2);
    short* Wt    = (short*)alloc((size_t)3 * 65536 * 2);
    float* inv_in  = (float*)alloc(400 * 4);
    float* csum    = (float*)alloc(400 * 4);
    int*   csr_off = (int*)alloc(401 * 4);
    int*   csr_srcv= (int*)alloc(CSR_CAP * 4);
    float* cf1     = (float*)alloc(CSR_CAP * 4);
    float* cf2     = (float*)alloc(CSR_CAP * 4);
    float* stats   = (float*)alloc(12 * 4);

    hipMemsetAsync(stats, 0, 12 * 4, stream);
    k_prep<<<1349, 256, 0, stream>>>(src, dst, ew, gcn_W, inp, W_in, b_in,
                                     gcn_b + 512, inv_in, csum, csr_off,
                                     csr_srcv, cf1, cf2, Wt, xproj, stats);

    const int lefts[4] = {0, 4, 7, 10};
    const size_t RB = (size_t)ROWS_BAND * HID;
    for (int it = 0; it < 4; ++it) {
        int t1 = (it == 0) ? 1 : lefts[it];
        int t3 = (it == 0) ? 3 : lefts[it] + 2;
        const short* hlp = (it == 0) ? xproj : ((it & 1) ? hl0 : hl1);
        const float* stA = (it == 0) ? stats + 8 : stats + (it - 1) * 2;
        short* cur = (it & 1) ? hl1 : hl0;
        k_layer<0><<<400, 256, 0, stream>>>(hlp, xproj + (size_t)t3 * BAND, stA, csum,
                                            inv_in, csr_off, csr_srcv, cf1, cf2,
                                            Wt, gcn_b,
                                            nullptr, nullptr, nullptr, nullptr,
                                            hA, nullptr);
        k_layer<1><<<400, 256, 0, stream>>>(hA, hA + RB, stats + 8, csum,
                                            inv_in, csr_off, csr_srcv, cf1, cf2,
                                            Wt + 65536, gcn_b + 256,
                                            nullptr, nullptr, nullptr, nullptr,
                                            hB, nullptr);
        k_layer<2><<<400, 256, 0, stream>>>(hB, hB + RB, stats + 8, csum,
                                            inv_in, csr_off, csr_srcv, cf1, cf2,
                                            Wt + 131072, gcn_b + 512,
                                            hlp, stA, xproj + (size_t)t1 * BAND,
                                            xproj + (size_t)t3 * BAND,
                                            cur, stats + it * 2);
    }

    k_head<<<dim3(NN, BB), 256, 0, stream>>>(hl1, stats + 6, W1, b1, W2, b2, out);
}

// Round 16
// 283.714 us; speedup vs baseline: 1.1167x; 1.1167x over previous
//
#include <hip/hip_runtime.h>

// Problem constants (fixed by the reference)
#define BB 16
#define HIS 13
#define NN 400
#define DIN 16
#define HID 256
#define PRED 12
#define NE 9600
#define EPSF 1e-5f
#define HSZ ((size_t)25600*256)            // full h element count (LN stats denom)
#define BAND ((size_t)NN*BB*HID)           // 1,638,400 elems (one t-band)
#define ROWS_BAND (NN*BB)                  // 6400 rows per band
#define CSR_CAP 6144

typedef __attribute__((ext_vector_type(8))) short short8v;
typedef __attribute__((ext_vector_type(4))) float f32x4;

__device__ __forceinline__ short f2bf(float x) {
    unsigned u = __float_as_uint(x);
    return (short)((u + 0x7FFF + ((u >> 16) & 1)) >> 16);
}
__device__ __forceinline__ float bf2f(short x) {
    return __uint_as_float(((unsigned)(unsigned short)x) << 16);
}
__device__ __forceinline__ void gload16(const void* g, void* l) {
    __builtin_amdgcn_global_load_lds((const __attribute__((address_space(1))) void*)g,
                                     (__attribute__((address_space(3))) void*)l,
                                     16, 0, 0);
}

// ------------------------------------------------------------ fused prep
// block 0        : CSR build (src structure exploited, round 14)
// blocks 1..48   : Wt tile transpose
// blocks 49..1348: input projections — identical to round 14 except the x rows
//                  are staged once through LDS (coalesced) instead of per-thread
//                  wave-uniform scalar loads.
__global__ __launch_bounds__(256) void k_prep(
    const int* __restrict__ src, const int* __restrict__ dst,
    const float* __restrict__ ew, const float* __restrict__ gcn_W,
    const float* __restrict__ inp, const float* __restrict__ W_in,
    const float* __restrict__ b_in, const float* __restrict__ gb2,
    float* __restrict__ inv_in, float* __restrict__ csum,
    int* __restrict__ csr_off, int* __restrict__ csr_src,
    float* __restrict__ cf1, float* __restrict__ cf2,
    short* __restrict__ Wt, short* __restrict__ xproj,
    float* __restrict__ stats)
{
    __shared__ __align__(16) char SM[17408];
    int t = threadIdx.x, bi = blockIdx.x;
    if (bi == 0) {
        int* ideg  = (int*)SM;             // 400
        int* cnt   = ideg + 400;           // 400
        int* offl  = cnt + 400;            // 401
        int* scan_t = offl + 401;          // 256
        float* csuml = (float*)(scan_t + 256); // 400
        for (int g = t; g < 400; g += 256) { ideg[g] = 0; cnt[g] = 0; csuml[g] = 0.f; }
        if (t == 9) stats[9] = (1.0f - EPSF) * (float)HSZ;   // identity affine slot
        __syncthreads();
        for (int e = t; e < 3200; e += 256) atomicAdd(&ideg[dst[e]], 1);
        __syncthreads();
        int s = 0, p0 = 0, p1 = 0;
        if (t < 200) {
            p0 = (ideg[2 * t] + 7) & ~7;
            p1 = (ideg[2 * t + 1] + 7) & ~7;
            s = p0 + p1;
        }
        scan_t[t] = s;
        __syncthreads();
        for (int o = 1; o < 256; o <<= 1) {
            int v = (t >= o) ? scan_t[t - o] : 0;
            __syncthreads();
            scan_t[t] += v;
            __syncthreads();
        }
        if (t < 200) { int base = scan_t[t] - s; offl[2 * t] = base; offl[2 * t + 1] = base + p0; }
        if (t == 255) offl[400] = scan_t[255];
        __syncthreads();
        int cap = offl[400];
        for (int g = t; g < 401; g += 256) csr_off[g] = offl[g];
        for (int g = t; g < 400; g += 256) inv_in[g] = rsqrtf(fmaxf((float)ideg[g], 1.f));
        for (int i = t; i < cap; i += 256) { csr_src[i] = 0; cf1[i] = 0.f; cf2[i] = 0.f; }
        __syncthreads();
        float rs16 = rsqrtf(16.0f), rs8 = rsqrtf(8.0f);
        for (int e = t; e < 3200; e += 256) {
            int d = dst[e];
            int r = e >> 3;                 // src structure: repeat(arange(400), 8)
            int p = offl[d] + atomicAdd(&cnt[d], 1);
            float w = ew[e];
            float c1 = w * rs16;
            csr_src[p] = r;
            cf1[p] = c1;
            cf2[p] = w * rs8;
            atomicAdd(&csuml[d], c1);
        }
        __syncthreads();
        for (int g = t; g < 400; g += 256) csum[g] = csuml[g];
    } else if (bi <= 48) {
        float (*S)[65] = (float(*)[65])SM;
        int tile = bi - 1;
        int l = tile / 16, sub = tile % 16;
        int k0 = (sub >> 2) * 64, n0 = (sub & 3) * 64;
        int tr = t >> 6, tc = t & 63;
#pragma unroll
        for (int i = 0; i < 16; ++i) {
            int r = i * 4 + tr;
            S[r][tc] = gcn_W[(size_t)l * 65536 + (size_t)(k0 + r) * 256 + n0 + tc];
        }
        __syncthreads();
#pragma unroll
        for (int i = 0; i < 16; ++i) {
            int n = i * 4 + tr;
            Wt[(size_t)l * 65536 + (size_t)(n0 + n) * 256 + k0 + tc] = f2bf(S[tc][n]);
        }
    } else {
        float* xs   = (float*)SM;            // 4 jobs x 16 b x 16 d = 4KB
        float* rbuf = (float*)(SM + 4096);   // 8 floats
        float wr[16];
#pragma unroll
        for (int d = 0; d < 16; ++d) wr[d] = W_in[d * 256 + t];
        float bvv = b_in[t];
        int job0 = (bi - 49) * 4;
        int time = job0 / 400;
        int n0 = job0 % 400;
        bool isStat = (time == 2 || time == 5 || time == 8 || time == 11);
        float gb = isStat ? gb2[t] : 0.f;
        // coalesced stage: one float4 per thread covers all 4 jobs' x rows
        {
            int j = t >> 6, b = (t >> 2) & 15, q = t & 3;
            const float4 v = *(const float4*)
                &inp[(((size_t)b * HIS + time) * NN + (n0 + j)) * DIN + q * 4];
            *(float4*)&xs[(j * 16 + b) * 16 + q * 4] = v;
        }
        __syncthreads();
        float s1 = 0.f, s2 = 0.f;
#pragma unroll
        for (int j = 0; j < 4; ++j) {
            float acc[16];
#pragma unroll
            for (int b = 0; b < 16; ++b) acc[b] = bvv;
#pragma unroll
            for (int b = 0; b < 16; ++b) {
                const float* xr = &xs[(j * 16 + b) * 16];   // broadcast LDS reads
                float a = acc[b];
#pragma unroll
                for (int d = 0; d < 16; ++d) a = fmaf(xr[d], wr[d], a);
                acc[b] = a;
            }
            if (isStat) {
#pragma unroll
                for (int b = 0; b < 16; ++b) {
                    float v = acc[b] + gb;
                    s1 += v; s2 += v * v;
                }
            } else {
                size_t gbase = (size_t)time * BAND + ((size_t)(n0 + j) * 16) * 256 + t;
#pragma unroll
                for (int b = 0; b < 16; ++b) xproj[gbase + (size_t)b * 256] = f2bf(acc[b]);
            }
        }
        if (isStat) {
#pragma unroll
            for (int o = 32; o > 0; o >>= 1) {
                s1 += __shfl_down(s1, o, 64);
                s2 += __shfl_down(s2, o, 64);
            }
            int wid = t >> 6, lane = t & 63;
            if (lane == 0) { rbuf[wid] = s1; rbuf[4 + wid] = s2; }
            __syncthreads();
            if (t == 0) {
                int it = (time - 2) / 3;
                atomicAdd(&stats[it * 2],     rbuf[0] + rbuf[1] + rbuf[2] + rbuf[3]);
                atomicAdd(&stats[it * 2 + 1], rbuf[4] + rbuf[5] + rbuf[6] + rbuf[7]);
            }
        }
    }
}

// ------------------------------------------------------------ fused agg + MFMA GEMM
// (verbatim round 14 — proven best)
template <int MODE>
__global__ __launch_bounds__(256) void k_layer(
    const short* __restrict__ hX, const short* __restrict__ hY,
    const float* __restrict__ stA, const float* __restrict__ csum,
    const float* __restrict__ inv_in, const int* __restrict__ csr_off,
    const int* __restrict__ csr_src, const float* __restrict__ cf1,
    const float* __restrict__ cf2,
    const short* __restrict__ Bt, const float* __restrict__ bias,
    const short* __restrict__ resX0, const float* __restrict__ stR,
    const short* __restrict__ resX1, const short* __restrict__ resY,
    short* __restrict__ C, float* __restrict__ stats)
{
    __shared__ short As[32][264];
    __shared__ short Bs[2][8192];
    __shared__ float red[512];
    int tid = threadIdx.x;
    int wid = tid >> 6, l = tid & 63;
    int l15 = l & 15, l4 = l >> 4;
    int blk = blockIdx.x;
    int isY = blk >= 200;
    int gl = (isY ? blk - 200 : blk) * 2;
    int rowL0 = gl * 16;
    int wn = wid * 64;
    const short* hsrc = isY ? hY : hX;
    const float* cf = isY ? cf2 : cf1;

    float am = 1.f, moff = 0.f;
    if (MODE == 0 && !isY) {
        float mean = stA[0] * (1.f / (float)HSZ);
        float var  = stA[1] * (1.f / (float)HSZ) - mean * mean;
        float istd = rsqrtf(var + EPSF);
        am = istd; moff = mean * istd;
    }
    int br = l >> 2;
    int kd = (l & 3) ^ ((br >> 1) & 3);
    for (int ch = wid; ch < 16; ch += 4)
        gload16(Bt + ((size_t)(ch * 16 + br)) * 256 + kd * 8, &Bs[0][ch * 512]);

    {
        int b = tid >> 4, hsc = (tid & 15) * 16;
        const size_t lane_off = (size_t)b * HID + hsc;
        for (int gi = 0; gi < 2; ++gi) {
            int g = gl + gi;
            int beg = csr_off[g], end = csr_off[g + 1];
            float acc[16];
#pragma unroll
            for (int i = 0; i < 16; ++i) acc[i] = 0.f;
            for (int j = beg; j < end; j += 8) {
                int ss[8]; float cc[8];
#pragma unroll
                for (int u = 0; u < 8; ++u) { ss[u] = csr_src[j + u]; cc[u] = cf[j + u]; }
                short8v va[8], vb[8];
#pragma unroll
                for (int u = 0; u < 8; ++u) {
                    const short8v* q = (const short8v*)&hsrc[(size_t)ss[u] * 4096 + lane_off];
                    va[u] = q[0]; vb[u] = q[1];
                }
#pragma unroll
                for (int u = 0; u < 8; ++u) {
#pragma unroll
                    for (int i = 0; i < 8; ++i) {
                        acc[i]     = fmaf(cc[u], bf2f(va[u][i]), acc[i]);
                        acc[8 + i] = fmaf(cc[u], bf2f(vb[u][i]), acc[8 + i]);
                    }
                }
            }
            float s = inv_in[g];
            float addv = (MODE == 0 && !isY) ? (-moff * csum[g]) : 0.f;
            short8v o0, o1;
#pragma unroll
            for (int i = 0; i < 8; ++i) o0[i] = f2bf(s * fmaf(am, acc[i], addv));
#pragma unroll
            for (int i = 0; i < 8; ++i) o1[i] = f2bf(s * fmaf(am, acc[8 + i], addv));
            int row = gi * 16 + b;
            *(short8v*)&As[row][hsc]     = o0;
            *(short8v*)&As[row][hsc + 8] = o1;
        }
    }
    __syncthreads();

    f32x4 cacc[2][4] = {};
    int xsw = (l4 ^ ((l15 >> 1) & 3)) * 8;
    for (int kc = 0; kc < 8; ++kc) {
        int cur = kc & 1;
        if (kc < 7) {
            int k0n = (kc + 1) * 32;
            for (int ch = wid; ch < 16; ch += 4)
                gload16(Bt + ((size_t)(ch * 16 + br)) * 256 + k0n + kd * 8,
                        &Bs[cur ^ 1][ch * 512]);
        }
        int k0 = kc * 32;
        short8v av[2], bv[4];
#pragma unroll
        for (int mi = 0; mi < 2; ++mi)
            av[mi] = *(const short8v*)&As[mi * 16 + l15][k0 + l4 * 8];
#pragma unroll
        for (int ni = 0; ni < 4; ++ni)
            bv[ni] = *(const short8v*)&Bs[cur][(wn + ni * 16 + l15) * 32 + xsw];
#pragma unroll
        for (int mi = 0; mi < 2; ++mi)
#pragma unroll
            for (int ni = 0; ni < 4; ++ni)
                cacc[mi][ni] = __builtin_amdgcn_mfma_f32_16x16x32_bf16(
                    av[mi], bv[ni], cacc[mi][ni], 0, 0, 0);
        __syncthreads();
    }

    if (MODE <= 1) {
#pragma unroll
        for (int ni = 0; ni < 4; ++ni) {
            int col = wn + ni * 16 + l15;
            float bvv = bias[col];
#pragma unroll
            for (int mi = 0; mi < 2; ++mi) {
#pragma unroll
                for (int r = 0; r < 4; ++r) {
                    float v = fmaxf(cacc[mi][ni][r] + bvv, 0.f);
                    As[mi * 16 + l4 * 4 + r][col] = f2bf(v);
                }
            }
        }
        __syncthreads();
        int row = tid >> 3, cs = (tid & 7) * 32;
        size_t gb = ((size_t)(isY ? ROWS_BAND : 0) + rowL0 + row) * HID + cs;
#pragma unroll
        for (int i = 0; i < 4; ++i)
            *(short8v*)&C[gb + i * 8] = *(const short8v*)&As[row][cs + i * 8];
    } else {
        float s1 = 0.f, s2 = 0.f;
        if (!isY) {
            float meanR = stR[0] * (1.f / (float)HSZ);
            float varR  = stR[1] * (1.f / (float)HSZ) - meanR * meanR;
            float istdR = rsqrtf(varR + EPSF);
#pragma unroll
            for (int ni = 0; ni < 4; ++ni) {
                int col = wn + ni * 16 + l15;
                float bvv = bias[col];
#pragma unroll
                for (int mi = 0; mi < 2; ++mi) {
#pragma unroll
                    for (int r = 0; r < 4; ++r) {
                        int rowg = rowL0 + mi * 16 + l4 * 4 + r;
                        size_t ix = (size_t)rowg * HID + col;
                        float base = cacc[mi][ni][r] + bvv;
                        float v1 = base + (bf2f(resX0[ix]) - meanR) * istdR;
                        float v2 = base + bf2f(resX1[ix]);
                        s1 += v1 + v2;
                        s2 += v1 * v1 + v2 * v2;
                    }
                }
            }
        } else {
#pragma unroll
            for (int ni = 0; ni < 4; ++ni) {
                int col = wn + ni * 16 + l15;
                float bvv = bias[col];
#pragma unroll
                for (int mi = 0; mi < 2; ++mi) {
#pragma unroll
                    for (int r = 0; r < 4; ++r) {
                        int rowl = mi * 16 + l4 * 4 + r;
                        size_t ix = (size_t)(rowL0 + rowl) * HID + col;
                        float v = cacc[mi][ni][r] + bvv + bf2f(resY[ix]);
                        s1 += v; s2 += v * v;
                        As[rowl][col] = f2bf(v);
                    }
                }
            }
            __syncthreads();
            int row = tid >> 3, cs = (tid & 7) * 32;
            size_t gb = (size_t)(rowL0 + row) * HID + cs;
#pragma unroll
            for (int i = 0; i < 4; ++i)
                *(short8v*)&C[gb + i * 8] = *(const short8v*)&As[row][cs + i * 8];
        }
        red[tid] = s1; red[256 + tid] = s2;
        __syncthreads();
        for (int o = 128; o > 0; o >>= 1) {
            if (tid < o) { red[tid] += red[tid + o]; red[256 + tid] += red[256 + tid + o]; }
            __syncthreads();
        }
        if (tid == 0) { atomicAdd(&stats[0], red[0]); atomicAdd(&stats[1], red[256]); }
    }
}

// ---------------------------------------------------------------- head
__global__ void k_head(const short* __restrict__ hlast, const float* __restrict__ st,
                       const float* __restrict__ W1, const float* __restrict__ b1,
                       const float* __restrict__ W2, const float* __restrict__ b2,
                       float* __restrict__ out) {
    float mean = st[0] * (1.0f / (float)HSZ);
    float var  = st[1] * (1.0f / (float)HSZ) - mean * mean;
    float istd = rsqrtf(var + EPSF);
    int n = blockIdx.x, b = blockIdx.y, tid = threadIdx.x;
    float v  = (bf2f(hlast[((size_t)n * BB + b) * HID + tid]) - mean) * istd;
    float w2 = W2[tid];
    float b2v = b2[0];
    __shared__ float ps[4];
    for (int p = 0; p < PRED; ++p) {
        float t = fmaxf(fmaf(v, W1[p], b1[p]), 0.f) * w2;
#pragma unroll
        for (int o = 32; o > 0; o >>= 1) t += __shfl_down(t, o, 64);
        int wid = tid >> 6, lane = tid & 63;
        if (lane == 0) ps[wid] = t;
        __syncthreads();
        if (tid == 0) out[(size_t)(b * PRED + p) * NN + n] = ps[0] + ps[1] + ps[2] + ps[3] + b2v;
        __syncthreads();
    }
}

// ---------------------------------------------------------------- launch
extern "C" void kernel_launch(void* const* d_in, const int* in_sizes, int n_in,
                              void* d_out, int out_size, void* d_ws, size_t ws_size,
                              hipStream_t stream) {
    const float* inp   = (const float*)d_in[0];
    const float* W_in  = (const float*)d_in[1];
    const float* b_in  = (const float*)d_in[2];
    const float* gcn_W = (const float*)d_in[3];
    const float* gcn_b = (const float*)d_in[4];
    const float* W1    = (const float*)d_in[5];
    const float* b1    = (const float*)d_in[6];
    const float* W2    = (const float*)d_in[7];
    const float* b2    = (const float*)d_in[8];
    const float* ew    = (const float*)d_in[9];
    const int*   src   = (const int*)d_in[10];
    const int*   dst   = (const int*)d_in[11];
    float* out = (float*)d_out;

    char* w = (char*)d_ws;
    auto alloc = [&](size_t bytes) {
        char* p = w;
        w += (bytes + 255) & ~(size_t)255;
        return p;
    };
    short* hA    = (short*)alloc((size_t)2 * ROWS_BAND * HID * 2);  // compact [X|Y]
    short* hB    = (short*)alloc((size_t)2 * ROWS_BAND * HID * 2);
    short* hl0   = (short*)alloc(BAND * 2);
    short* hl1   = (short*)alloc(BAND * 2);
    short* xproj = (short*)alloc((size_t)13 * BAND * 2);
    short* Wt    = (short*)alloc((size_t)3 * 65536 * 2);
    float* inv_in  = (float*)alloc(400 * 4);
    float* csum    = (float*)alloc(400 * 4);
    int*   csr_off = (int*)alloc(401 * 4);
    int*   csr_srcv= (int*)alloc(CSR_CAP * 4);
    float* cf1     = (float*)alloc(CSR_CAP * 4);
    float* cf2     = (float*)alloc(CSR_CAP * 4);
    float* stats   = (float*)alloc(12 * 4);

    hipMemsetAsync(stats, 0, 12 * 4, stream);
    k_prep<<<1349, 256, 0, stream>>>(src, dst, ew, gcn_W, inp, W_in, b_in,
                                     gcn_b + 512, inv_in, csum, csr_off,
                                     csr_srcv, cf1, cf2, Wt, xproj, stats);

    const int lefts[4] = {0, 4, 7, 10};
    const size_t RB = (size_t)ROWS_BAND * HID;
    for (int it = 0; it < 4; ++it) {
        int t1 = (it == 0) ? 1 : lefts[it];
        int t3 = (it == 0) ? 3 : lefts[it] + 2;
        const short* hlp = (it == 0) ? xproj : ((it & 1) ? hl0 : hl1);
        const float* stA = (it == 0) ? stats + 8 : stats + (it - 1) * 2;
        short* cur = (it & 1) ? hl1 : hl0;
        k_layer<0><<<400, 256, 0, stream>>>(hlp, xproj + (size_t)t3 * BAND, stA, csum,
                                            inv_in, csr_off, csr_srcv, cf1, cf2,
                                            Wt, gcn_b,
                                            nullptr, nullptr, nullptr, nullptr,
                                            hA, nullptr);
        k_layer<1><<<400, 256, 0, stream>>>(hA, hA + RB, stats + 8, csum,
                                            inv_in, csr_off, csr_srcv, cf1, cf2,
                                            Wt + 65536, gcn_b + 256,
                                            nullptr, nullptr, nullptr, nullptr,
                                            hB, nullptr);
        k_layer<2><<<400, 256, 0, stream>>>(hB, hB + RB, stats + 8, csum,
                                            inv_in, csr_off, csr_srcv, cf1, cf2,
                                            Wt + 131072, gcn_b + 512,
                                            hlp, stA, xproj + (size_t)t1 * BAND,
                                            xproj + (size_t)t3 * BAND,
                                            cur, stats + it * 2);
    }

    k_head<<<dim3(NN, BB), 256, 0, stream>>>(hl1, stats + 6, W1, b1, W2, b2, out);
}

// Round 17
// 282.665 us; speedup vs baseline: 1.1208x; 1.0037x over previous
//
#include <hip/hip_runtime.h>

// Problem constants (fixed by the reference)
#define BB 16
#define HIS 13
#define NN 400
#define DIN 16
#define HID 256
#define PRED 12
#define NE 9600
#define EPSF 1e-5f
#define HSZ ((size_t)25600*256)            // full h element count (LN stats denom)
#define BAND ((size_t)NN*BB*HID)           // 1,638,400 elems (one t-band)
#define ROWS_BAND (NN*BB)                  // 6400 rows per band
#define CSR_CAP 6144

typedef __attribute__((ext_vector_type(8))) short short8v;
typedef __attribute__((ext_vector_type(4))) float f32x4;

__device__ __forceinline__ short f2bf(float x) {
    unsigned u = __float_as_uint(x);
    return (short)((u + 0x7FFF + ((u >> 16) & 1)) >> 16);
}
__device__ __forceinline__ float bf2f(short x) {
    return __uint_as_float(((unsigned)(unsigned short)x) << 16);
}
__device__ __forceinline__ void gload16(const void* g, void* l) {
    __builtin_amdgcn_global_load_lds((const __attribute__((address_space(1))) void*)g,
                                     (__attribute__((address_space(3))) void*)l,
                                     16, 0, 0);
}

// ------------------------------------------------------------ fused prep
// (verbatim round 16)
__global__ __launch_bounds__(256) void k_prep(
    const int* __restrict__ src, const int* __restrict__ dst,
    const float* __restrict__ ew, const float* __restrict__ gcn_W,
    const float* __restrict__ inp, const float* __restrict__ W_in,
    const float* __restrict__ b_in, const float* __restrict__ gb2,
    float* __restrict__ inv_in, float* __restrict__ csum,
    int* __restrict__ csr_off, int* __restrict__ csr_src,
    float* __restrict__ cf1, float* __restrict__ cf2,
    short* __restrict__ Wt, short* __restrict__ xproj,
    float* __restrict__ stats)
{
    __shared__ __align__(16) char SM[17408];
    int t = threadIdx.x, bi = blockIdx.x;
    if (bi == 0) {
        int* ideg  = (int*)SM;             // 400
        int* cnt   = ideg + 400;           // 400
        int* offl  = cnt + 400;            // 401
        int* scan_t = offl + 401;          // 256
        float* csuml = (float*)(scan_t + 256); // 400
        for (int g = t; g < 400; g += 256) { ideg[g] = 0; cnt[g] = 0; csuml[g] = 0.f; }
        if (t == 9) stats[9] = (1.0f - EPSF) * (float)HSZ;   // identity affine slot
        __syncthreads();
        for (int e = t; e < 3200; e += 256) atomicAdd(&ideg[dst[e]], 1);
        __syncthreads();
        int s = 0, p0 = 0, p1 = 0;
        if (t < 200) {
            p0 = (ideg[2 * t] + 7) & ~7;
            p1 = (ideg[2 * t + 1] + 7) & ~7;
            s = p0 + p1;
        }
        scan_t[t] = s;
        __syncthreads();
        for (int o = 1; o < 256; o <<= 1) {
            int v = (t >= o) ? scan_t[t - o] : 0;
            __syncthreads();
            scan_t[t] += v;
            __syncthreads();
        }
        if (t < 200) { int base = scan_t[t] - s; offl[2 * t] = base; offl[2 * t + 1] = base + p0; }
        if (t == 255) offl[400] = scan_t[255];
        __syncthreads();
        int cap = offl[400];
        for (int g = t; g < 401; g += 256) csr_off[g] = offl[g];
        for (int g = t; g < 400; g += 256) inv_in[g] = rsqrtf(fmaxf((float)ideg[g], 1.f));
        for (int i = t; i < cap; i += 256) { csr_src[i] = 0; cf1[i] = 0.f; cf2[i] = 0.f; }
        __syncthreads();
        float rs16 = rsqrtf(16.0f), rs8 = rsqrtf(8.0f);
        for (int e = t; e < 3200; e += 256) {
            int d = dst[e];
            int r = e >> 3;                 // src structure: repeat(arange(400), 8)
            int p = offl[d] + atomicAdd(&cnt[d], 1);
            float w = ew[e];
            float c1 = w * rs16;
            csr_src[p] = r;
            cf1[p] = c1;
            cf2[p] = w * rs8;
            atomicAdd(&csuml[d], c1);
        }
        __syncthreads();
        for (int g = t; g < 400; g += 256) csum[g] = csuml[g];
    } else if (bi <= 48) {
        float (*S)[65] = (float(*)[65])SM;
        int tile = bi - 1;
        int l = tile / 16, sub = tile % 16;
        int k0 = (sub >> 2) * 64, n0 = (sub & 3) * 64;
        int tr = t >> 6, tc = t & 63;
#pragma unroll
        for (int i = 0; i < 16; ++i) {
            int r = i * 4 + tr;
            S[r][tc] = gcn_W[(size_t)l * 65536 + (size_t)(k0 + r) * 256 + n0 + tc];
        }
        __syncthreads();
#pragma unroll
        for (int i = 0; i < 16; ++i) {
            int n = i * 4 + tr;
            Wt[(size_t)l * 65536 + (size_t)(n0 + n) * 256 + k0 + tc] = f2bf(S[tc][n]);
        }
    } else {
        float* xs   = (float*)SM;            // 4 jobs x 16 b x 16 d = 4KB
        float* rbuf = (float*)(SM + 4096);   // 8 floats
        float wr[16];
#pragma unroll
        for (int d = 0; d < 16; ++d) wr[d] = W_in[d * 256 + t];
        float bvv = b_in[t];
        int job0 = (bi - 49) * 4;
        int time = job0 / 400;
        int n0 = job0 % 400;
        bool isStat = (time == 2 || time == 5 || time == 8 || time == 11);
        float gb = isStat ? gb2[t] : 0.f;
        // coalesced stage: one float4 per thread covers all 4 jobs' x rows
        {
            int j = t >> 6, b = (t >> 2) & 15, q = t & 3;
            const float4 v = *(const float4*)
                &inp[(((size_t)b * HIS + time) * NN + (n0 + j)) * DIN + q * 4];
            *(float4*)&xs[(j * 16 + b) * 16 + q * 4] = v;
        }
        __syncthreads();
        float s1 = 0.f, s2 = 0.f;
#pragma unroll
        for (int j = 0; j < 4; ++j) {
            float acc[16];
#pragma unroll
            for (int b = 0; b < 16; ++b) acc[b] = bvv;
#pragma unroll
            for (int b = 0; b < 16; ++b) {
                const float* xr = &xs[(j * 16 + b) * 16];   // broadcast LDS reads
                float a = acc[b];
#pragma unroll
                for (int d = 0; d < 16; ++d) a = fmaf(xr[d], wr[d], a);
                acc[b] = a;
            }
            if (isStat) {
#pragma unroll
                for (int b = 0; b < 16; ++b) {
                    float v = acc[b] + gb;
                    s1 += v; s2 += v * v;
                }
            } else {
                size_t gbase = (size_t)time * BAND + ((size_t)(n0 + j) * 16) * 256 + t;
#pragma unroll
                for (int b = 0; b < 16; ++b) xproj[gbase + (size_t)b * 256] = f2bf(acc[b]);
            }
        }
        if (isStat) {
#pragma unroll
            for (int o = 32; o > 0; o >>= 1) {
                s1 += __shfl_down(s1, o, 64);
                s2 += __shfl_down(s2, o, 64);
            }
            int wid = t >> 6, lane = t & 63;
            if (lane == 0) { rbuf[wid] = s1; rbuf[4 + wid] = s2; }
            __syncthreads();
            if (t == 0) {
                int it = (time - 2) / 3;
                atomicAdd(&stats[it * 2],     rbuf[0] + rbuf[1] + rbuf[2] + rbuf[3]);
                atomicAdd(&stats[it * 2 + 1], rbuf[4] + rbuf[5] + rbuf[6] + rbuf[7]);
            }
        }
    }
}

// ------------------------------------------------------------ fused agg + MFMA GEMM
// Round-14 body + s_setprio(1) around the MFMA cluster (T5: co-resident blocks
// are phase-desynced — gather length varies per g — so MFMA waves get priority
// over the other block's gather/stage loads).
template <int MODE>
__global__ __launch_bounds__(256) void k_layer(
    const short* __restrict__ hX, const short* __restrict__ hY,
    const float* __restrict__ stA, const float* __restrict__ csum,
    const float* __restrict__ inv_in, const int* __restrict__ csr_off,
    const int* __restrict__ csr_src, const float* __restrict__ cf1,
    const float* __restrict__ cf2,
    const short* __restrict__ Bt, const float* __restrict__ bias,
    const short* __restrict__ resX0, const float* __restrict__ stR,
    const short* __restrict__ resX1, const short* __restrict__ resY,
    short* __restrict__ C, float* __restrict__ stats)
{
    __shared__ short As[32][264];
    __shared__ short Bs[2][8192];
    __shared__ float red[512];
    int tid = threadIdx.x;
    int wid = tid >> 6, l = tid & 63;
    int l15 = l & 15, l4 = l >> 4;
    int blk = blockIdx.x;
    int isY = blk >= 200;
    int gl = (isY ? blk - 200 : blk) * 2;
    int rowL0 = gl * 16;
    int wn = wid * 64;
    const short* hsrc = isY ? hY : hX;
    const float* cf = isY ? cf2 : cf1;

    float am = 1.f, moff = 0.f;
    if (MODE == 0 && !isY) {
        float mean = stA[0] * (1.f / (float)HSZ);
        float var  = stA[1] * (1.f / (float)HSZ) - mean * mean;
        float istd = rsqrtf(var + EPSF);
        am = istd; moff = mean * istd;
    }
    int br = l >> 2;
    int kd = (l & 3) ^ ((br >> 1) & 3);
    for (int ch = wid; ch < 16; ch += 4)
        gload16(Bt + ((size_t)(ch * 16 + br)) * 256 + kd * 8, &Bs[0][ch * 512]);

    {
        int b = tid >> 4, hsc = (tid & 15) * 16;
        const size_t lane_off = (size_t)b * HID + hsc;
        for (int gi = 0; gi < 2; ++gi) {
            int g = gl + gi;
            int beg = csr_off[g], end = csr_off[g + 1];
            float acc[16];
#pragma unroll
            for (int i = 0; i < 16; ++i) acc[i] = 0.f;
            for (int j = beg; j < end; j += 8) {
                int ss[8]; float cc[8];
#pragma unroll
                for (int u = 0; u < 8; ++u) { ss[u] = csr_src[j + u]; cc[u] = cf[j + u]; }
                short8v va[8], vb[8];
#pragma unroll
                for (int u = 0; u < 8; ++u) {
                    const short8v* q = (const short8v*)&hsrc[(size_t)ss[u] * 4096 + lane_off];
                    va[u] = q[0]; vb[u] = q[1];
                }
#pragma unroll
                for (int u = 0; u < 8; ++u) {
#pragma unroll
                    for (int i = 0; i < 8; ++i) {
                        acc[i]     = fmaf(cc[u], bf2f(va[u][i]), acc[i]);
                        acc[8 + i] = fmaf(cc[u], bf2f(vb[u][i]), acc[8 + i]);
                    }
                }
            }
            float s = inv_in[g];
            float addv = (MODE == 0 && !isY) ? (-moff * csum[g]) : 0.f;
            short8v o0, o1;
#pragma unroll
            for (int i = 0; i < 8; ++i) o0[i] = f2bf(s * fmaf(am, acc[i], addv));
#pragma unroll
            for (int i = 0; i < 8; ++i) o1[i] = f2bf(s * fmaf(am, acc[8 + i], addv));
            int row = gi * 16 + b;
            *(short8v*)&As[row][hsc]     = o0;
            *(short8v*)&As[row][hsc + 8] = o1;
        }
    }
    __syncthreads();

    f32x4 cacc[2][4] = {};
    int xsw = (l4 ^ ((l15 >> 1) & 3)) * 8;
    for (int kc = 0; kc < 8; ++kc) {
        int cur = kc & 1;
        if (kc < 7) {
            int k0n = (kc + 1) * 32;
            for (int ch = wid; ch < 16; ch += 4)
                gload16(Bt + ((size_t)(ch * 16 + br)) * 256 + k0n + kd * 8,
                        &Bs[cur ^ 1][ch * 512]);
        }
        int k0 = kc * 32;
        short8v av[2], bv[4];
#pragma unroll
        for (int mi = 0; mi < 2; ++mi)
            av[mi] = *(const short8v*)&As[mi * 16 + l15][k0 + l4 * 8];
#pragma unroll
        for (int ni = 0; ni < 4; ++ni)
            bv[ni] = *(const short8v*)&Bs[cur][(wn + ni * 16 + l15) * 32 + xsw];
        __builtin_amdgcn_s_setprio(1);
#pragma unroll
        for (int mi = 0; mi < 2; ++mi)
#pragma unroll
            for (int ni = 0; ni < 4; ++ni)
                cacc[mi][ni] = __builtin_amdgcn_mfma_f32_16x16x32_bf16(
                    av[mi], bv[ni], cacc[mi][ni], 0, 0, 0);
        __builtin_amdgcn_s_setprio(0);
        __syncthreads();
    }

    if (MODE <= 1) {
#pragma unroll
        for (int ni = 0; ni < 4; ++ni) {
            int col = wn + ni * 16 + l15;
            float bvv = bias[col];
#pragma unroll
            for (int mi = 0; mi < 2; ++mi) {
#pragma unroll
                for (int r = 0; r < 4; ++r) {
                    float v = fmaxf(cacc[mi][ni][r] + bvv, 0.f);
                    As[mi * 16 + l4 * 4 + r][col] = f2bf(v);
                }
            }
        }
        __syncthreads();
        int row = tid >> 3, cs = (tid & 7) * 32;
        size_t gb = ((size_t)(isY ? ROWS_BAND : 0) + rowL0 + row) * HID + cs;
#pragma unroll
        for (int i = 0; i < 4; ++i)
            *(short8v*)&C[gb + i * 8] = *(const short8v*)&As[row][cs + i * 8];
    } else {
        float s1 = 0.f, s2 = 0.f;
        if (!isY) {
            float meanR = stR[0] * (1.f / (float)HSZ);
            float varR  = stR[1] * (1.f / (float)HSZ) - meanR * meanR;
            float istdR = rsqrtf(varR + EPSF);
#pragma unroll
            for (int ni = 0; ni < 4; ++ni) {
                int col = wn + ni * 16 + l15;
                float bvv = bias[col];
#pragma unroll
                for (int mi = 0; mi < 2; ++mi) {
#pragma unroll
                    for (int r = 0; r < 4; ++r) {
                        int rowg = rowL0 + mi * 16 + l4 * 4 + r;
                        size_t ix = (size_t)rowg * HID + col;
                        float base = cacc[mi][ni][r] + bvv;
                        float v1 = base + (bf2f(resX0[ix]) - meanR) * istdR;
                        float v2 = base + bf2f(resX1[ix]);
                        s1 += v1 + v2;
                        s2 += v1 * v1 + v2 * v2;
                    }
                }
            }
        } else {
#pragma unroll
            for (int ni = 0; ni < 4; ++ni) {
                int col = wn + ni * 16 + l15;
                float bvv = bias[col];
#pragma unroll
                for (int mi = 0; mi < 2; ++mi) {
#pragma unroll
                    for (int r = 0; r < 4; ++r) {
                        int rowl = mi * 16 + l4 * 4 + r;
                        size_t ix = (size_t)(rowL0 + rowl) * HID + col;
                        float v = cacc[mi][ni][r] + bvv + bf2f(resY[ix]);
                        s1 += v; s2 += v * v;
                        As[rowl][col] = f2bf(v);
                    }
                }
            }
            __syncthreads();
            int row = tid >> 3, cs = (tid & 7) * 32;
            size_t gb = (size_t)(rowL0 + row) * HID + cs;
#pragma unroll
            for (int i = 0; i < 4; ++i)
                *(short8v*)&C[gb + i * 8] = *(const short8v*)&As[row][cs + i * 8];
        }
        red[tid] = s1; red[256 + tid] = s2;
        __syncthreads();
        for (int o = 128; o > 0; o >>= 1) {
            if (tid < o) { red[tid] += red[tid + o]; red[256 + tid] += red[256 + tid + o]; }
            __syncthreads();
        }
        if (tid == 0) { atomicAdd(&stats[0], red[0]); atomicAdd(&stats[1], red[256]); }
    }
}

// ---------------------------------------------------------------- head
__global__ void k_head(const short* __restrict__ hlast, const float* __restrict__ st,
                       const float* __restrict__ W1, const float* __restrict__ b1,
                       const float* __restrict__ W2, const float* __restrict__ b2,
                       float* __restrict__ out) {
    float mean = st[0] * (1.0f / (float)HSZ);
    float var  = st[1] * (1.0f / (float)HSZ) - mean * mean;
    float istd = rsqrtf(var + EPSF);
    int n = blockIdx.x, b = blockIdx.y, tid = threadIdx.x;
    float v  = (bf2f(hlast[((size_t)n * BB + b) * HID + tid]) - mean) * istd;
    float w2 = W2[tid];
    float b2v = b2[0];
    __shared__ float ps[4];
    for (int p = 0; p < PRED; ++p) {
        float t = fmaxf(fmaf(v, W1[p], b1[p]), 0.f) * w2;
#pragma unroll
        for (int o = 32; o > 0; o >>= 1) t += __shfl_down(t, o, 64);
        int wid = tid >> 6, lane = tid & 63;
        if (lane == 0) ps[wid] = t;
        __syncthreads();
        if (tid == 0) out[(size_t)(b * PRED + p) * NN + n] = ps[0] + ps[1] + ps[2] + ps[3] + b2v;
        __syncthreads();
    }
}

// ---------------------------------------------------------------- launch
extern "C" void kernel_launch(void* const* d_in, const int* in_sizes, int n_in,
                              void* d_out, int out_size, void* d_ws, size_t ws_size,
                              hipStream_t stream) {
    const float* inp   = (const float*)d_in[0];
    const float* W_in  = (const float*)d_in[1];
    const float* b_in  = (const float*)d_in[2];
    const float* gcn_W = (const float*)d_in[3];
    const float* gcn_b = (const float*)d_in[4];
    const float* W1    = (const float*)d_in[5];
    const float* b1    = (const float*)d_in[6];
    const float* W2    = (const float*)d_in[7];
    const float* b2    = (const float*)d_in[8];
    const float* ew    = (const float*)d_in[9];
    const int*   src   = (const int*)d_in[10];
    const int*   dst   = (const int*)d_in[11];
    float* out = (float*)d_out;

    char* w = (char*)d_ws;
    auto alloc = [&](size_t bytes) {
        char* p = w;
        w += (bytes + 255) & ~(size_t)255;
        return p;
    };
    short* hA    = (short*)alloc((size_t)2 * ROWS_BAND * HID * 2);  // compact [X|Y]
    short* hB    = (short*)alloc((size_t)2 * ROWS_BAND * HID * 2);
    short* hl0   = (short*)alloc(BAND * 2);
    short* hl1   = (short*)alloc(BAND * 2);
    short* xproj = (short*)alloc((size_t)13 * BAND * 2);
    short* Wt    = (short*)alloc((size_t)3 * 65536 * 2);
    float* inv_in  = (float*)alloc(400 * 4);
    float* csum    = (float*)alloc(400 * 4);
    int*   csr_off = (int*)alloc(401 * 4);
    int*   csr_srcv= (int*)alloc(CSR_CAP * 4);
    float* cf1     = (float*)alloc(CSR_CAP * 4);
    float* cf2     = (float*)alloc(CSR_CAP * 4);
    float* stats   = (float*)alloc(12 * 4);

    hipMemsetAsync(stats, 0, 12 * 4, stream);
    k_prep<<<1349, 256, 0, stream>>>(src, dst, ew, gcn_W, inp, W_in, b_in,
                                     gcn_b + 512, inv_in, csum, csr_off,
                                     csr_srcv, cf1, cf2, Wt, xproj, stats);

    const int lefts[4] = {0, 4, 7, 10};
    const size_t RB = (size_t)ROWS_BAND * HID;
    for (int it = 0; it < 4; ++it) {
        int t1 = (it == 0) ? 1 : lefts[it];
        int t3 = (it == 0) ? 3 : lefts[it] + 2;
        const short* hlp = (it == 0) ? xproj : ((it & 1) ? hl0 : hl1);
        const float* stA = (it == 0) ? stats + 8 : stats + (it - 1) * 2;
        short* cur = (it & 1) ? hl1 : hl0;
        k_layer<0><<<400, 256, 0, stream>>>(hlp, xproj + (size_t)t3 * BAND, stA, csum,
                                            inv_in, csr_off, csr_srcv, cf1, cf2,
                                            Wt, gcn_b,
                                            nullptr, nullptr, nullptr, nullptr,
                                            hA, nullptr);
        k_layer<1><<<400, 256, 0, stream>>>(hA, hA + RB, stats + 8, csum,
                                            inv_in, csr_off, csr_srcv, cf1, cf2,
                                            Wt + 65536, gcn_b + 256,
                                            nullptr, nullptr, nullptr, nullptr,
                                            hB, nullptr);
        k_layer<2><<<400, 256, 0, stream>>>(hB, hB + RB, stats + 8, csum,
                                            inv_in, csr_off, csr_srcv, cf1, cf2,
                                            Wt + 131072, gcn_b + 512,
                                            hlp, stA, xproj + (size_t)t1 * BAND,
                                            xproj + (size_t)t3 * BAND,
                                            cur, stats + it * 2);
    }

    k_head<<<dim3(NN, BB), 256, 0, stream>>>(hl1, stats + 6, W1, b1, W2, b2, out);
}